// Round 3
// baseline (42382.809 us; speedup 1.0000x reference)
//
#include <hip/hip_runtime.h>
#include <cstdint>
#include <cstddef>

#ifndef __has_builtin
#define __has_builtin(x) 0
#endif

#define TSTEPS 50000
#define DDIM   768
#define GDIM   512   // 4*F gates
#define FDIM   128

typedef _Float16 half2_t __attribute__((ext_vector_type(2)));

__device__ __forceinline__ uint32_t pack2_rn(float a, float b) {
  uint16_t ua = __builtin_bit_cast(uint16_t, (_Float16)a);
  uint16_t ub = __builtin_bit_cast(uint16_t, (_Float16)b);
  return (uint32_t)ua | ((uint32_t)ub << 16);
}

__device__ __forceinline__ float fdot2f(uint32_t a, uint32_t b, float acc) {
#if __has_builtin(__builtin_amdgcn_fdot2)
  return __builtin_amdgcn_fdot2(__builtin_bit_cast(half2_t, a),
                                __builtin_bit_cast(half2_t, b), acc, false);
#else
  half2_t ha = __builtin_bit_cast(half2_t, a);
  half2_t hb = __builtin_bit_cast(half2_t, b);
  return acc + (float)ha[0] * (float)hb[0] + (float)ha[1] * (float)hb[1];
#endif
}

__device__ __forceinline__ float fast_sigmoid(float x) {
  float e = __builtin_amdgcn_exp2f(-1.4426950408889634f * x);
  return __builtin_amdgcn_rcpf(1.0f + e);
}

// Column permutation of pre2 so the scan's per-step load is one coalesced
// dword per thread. Scan thread tid=(j<<1)|s owns gate rows:
//   first  (col tid)      : s*128 + j        (i for s=0, f for s=1)
//   second (col tid+256)  : (2+s)*128 + j    (g for s=0, o for s=1)
__device__ __forceinline__ int rowmap(int c) {
  int hi = c >> 8;      // 0: first rows, 1: second rows
  int lo = c & 255;
  return (((hi << 1) | (lo & 1)) << 7) | (lo >> 1);
}

// ---------------------------------------------------------------------------
// pack Whh2 (512x128 f32) -> (512x64) packed half2, original row order
__global__ __launch_bounds__(256) void prep_whh(const float* __restrict__ whh,
                                                uint32_t* __restrict__ whh_pk) {
  int idx = blockIdx.x * 256 + threadIdx.x;
  if (idx >= GDIM * (FDIM / 2)) return;
  int j = idx >> 6, q = idx & 63;
  whh_pk[idx] = pack2_rn(whh[j * FDIM + 2 * q], whh[j * FDIM + 2 * q + 1]);
}

// ---------------------------------------------------------------------------
// pre2[:, c] = x @ Wih2[rowmap(c)] + (bih2+bhh2)[rowmap(c)]
__device__ __forceinline__ void store_row4(float* p, float a, float b, float c, float d) {
  *(float4*)p = make_float4(a, b, c, d);
}
__device__ __forceinline__ void store_row4(_Float16* p, float a, float b, float c, float d) {
  uint2 v; v.x = pack2_rn(a, b); v.y = pack2_rn(c, d);
  *(uint2*)p = v;
}

template <typename PT>
__global__ __launch_bounds__(256) void pre2_gemm(const float* __restrict__ X,
                                                 const float* __restrict__ Wih,
                                                 const float* __restrict__ bih,
                                                 const float* __restrict__ bhh,
                                                 PT* __restrict__ pre2) {
  __shared__ __align__(16) float As[32][68];
  __shared__ __align__(16) float Bs[32][68];
  const int tid = threadIdx.x;
  const int m0 = blockIdx.x * 64;
  const int n0 = blockIdx.y * 64;
  const int lr = tid >> 3;
  const int lk = (tid & 7) * 4;
  const int tx = tid & 15;
  const int ty = tid >> 4;

  float acc[4][4];
#pragma unroll
  for (int i = 0; i < 4; ++i)
#pragma unroll
    for (int j = 0; j < 4; ++j) acc[i][j] = 0.0f;

  int ar0 = m0 + lr;      if (ar0 > TSTEPS - 1) ar0 = TSTEPS - 1;
  int ar1 = m0 + lr + 32; if (ar1 > TSTEPS - 1) ar1 = TSTEPS - 1;
  const int br0 = rowmap(n0 + lr), br1 = rowmap(n0 + lr + 32);

#pragma unroll 1
  for (int k0 = 0; k0 < DDIM; k0 += 32) {
    float4 a0 = *(const float4*)&X[(size_t)ar0 * DDIM + k0 + lk];
    float4 a1 = *(const float4*)&X[(size_t)ar1 * DDIM + k0 + lk];
    float4 b0 = *(const float4*)&Wih[(size_t)br0 * DDIM + k0 + lk];
    float4 b1 = *(const float4*)&Wih[(size_t)br1 * DDIM + k0 + lk];
    __syncthreads();
    As[lk + 0][lr] = a0.x; As[lk + 1][lr] = a0.y; As[lk + 2][lr] = a0.z; As[lk + 3][lr] = a0.w;
    As[lk + 0][lr + 32] = a1.x; As[lk + 1][lr + 32] = a1.y; As[lk + 2][lr + 32] = a1.z; As[lk + 3][lr + 32] = a1.w;
    Bs[lk + 0][lr] = b0.x; Bs[lk + 1][lr] = b0.y; Bs[lk + 2][lr] = b0.z; Bs[lk + 3][lr] = b0.w;
    Bs[lk + 0][lr + 32] = b1.x; Bs[lk + 1][lr + 32] = b1.y; Bs[lk + 2][lr + 32] = b1.z; Bs[lk + 3][lr + 32] = b1.w;
    __syncthreads();
#pragma unroll
    for (int kk = 0; kk < 32; ++kk) {
      float4 av = *(const float4*)&As[kk][ty * 4];
      float4 bv = *(const float4*)&Bs[kk][tx * 4];
      acc[0][0] = fmaf(av.x, bv.x, acc[0][0]); acc[0][1] = fmaf(av.x, bv.y, acc[0][1]);
      acc[0][2] = fmaf(av.x, bv.z, acc[0][2]); acc[0][3] = fmaf(av.x, bv.w, acc[0][3]);
      acc[1][0] = fmaf(av.y, bv.x, acc[1][0]); acc[1][1] = fmaf(av.y, bv.y, acc[1][1]);
      acc[1][2] = fmaf(av.y, bv.z, acc[1][2]); acc[1][3] = fmaf(av.y, bv.w, acc[1][3]);
      acc[2][0] = fmaf(av.z, bv.x, acc[2][0]); acc[2][1] = fmaf(av.z, bv.y, acc[2][1]);
      acc[2][2] = fmaf(av.z, bv.z, acc[2][2]); acc[2][3] = fmaf(av.z, bv.w, acc[2][3]);
      acc[3][0] = fmaf(av.w, bv.x, acc[3][0]); acc[3][1] = fmaf(av.w, bv.y, acc[3][1]);
      acc[3][2] = fmaf(av.w, bv.z, acc[3][2]); acc[3][3] = fmaf(av.w, bv.w, acc[3][3]);
    }
  }

  float bias[4];
#pragma unroll
  for (int jj = 0; jj < 4; ++jj) {
    int rn = rowmap(n0 + tx * 4 + jj);
    bias[jj] = bih[rn] + bhh[rn];
  }
#pragma unroll
  for (int i = 0; i < 4; ++i) {
    int m = m0 + ty * 4 + i;
    if (m < TSTEPS) {
      store_row4(&pre2[(size_t)m * GDIM + n0 + tx * 4],
                 acc[i][0] + bias[0], acc[i][1] + bias[1],
                 acc[i][2] + bias[2], acc[i][3] + bias[3]);
    }
  }
}

// ---------------------------------------------------------------------------
// Sequential LSTM scan: 1 block, 256 threads (4 waves, 1/SIMD).
// Thread (j=tid>>1, s=tid&1): s=0 owns gate rows {i,g}, s=1 owns {f,o}.
// 32 uint4 of packed-half2 weights per thread, pinned in VGPRs via empty asm.
// h packed f16 in double-buffered LDS (broadcast reads). i*g computed locally
// on s=0, one shfl_xor to deliver it; c,h finalized on s=1. ONE barrier/step.
template <typename PT>
__global__ __launch_bounds__(256, 1) void lstm_scan(const PT* __restrict__ pre2,
                                                    const uint32_t* __restrict__ whh_pk,
                                                    const float* __restrict__ h0,
                                                    const float* __restrict__ c0,
                                                    uint32_t* __restrict__ hs2p) {
  const int tid = threadIdx.x;          // 0..255
  const int s = tid & 1;
  const int j = tid >> 1;               // 0..127
  const int rowA = (s << 7) | j;        // i (s=0) or f (s=1)
  const int rowB = ((2 + s) << 7) | j;  // g (s=0) or o (s=1)

  uint4 wa[16], wb[16];
  {
    const uint4* pA = (const uint4*)(whh_pk + (size_t)rowA * 64);
    const uint4* pB = (const uint4*)(whh_pk + (size_t)rowB * 64);
#pragma unroll
    for (int i = 0; i < 16; ++i) { wa[i] = pA[i]; wb[i] = pB[i]; }
  }
  // Pin every weight word in a VGPR; opaque to the compiler -> cannot be
  // rematerialized from memory inside the loop (round-2 failure mode).
#pragma unroll
  for (int i = 0; i < 16; ++i) {
    asm volatile("" : "+v"(wa[i].x), "+v"(wa[i].y), "+v"(wa[i].z), "+v"(wa[i].w));
    asm volatile("" : "+v"(wb[i].x), "+v"(wb[i].y), "+v"(wb[i].z), "+v"(wb[i].w));
  }

  __shared__ __align__(16) uint32_t hpk[2][64];  // packed h, double-buffered
  float c = c0[j];
  if (tid < 64) hpk[0][tid] = pack2_rn(h0[2 * tid], h0[2 * tid + 1]);
  __syncthreads();

  // act_a = sigmoid always (i or f). act_b: s=0 -> tanh (g), s=1 -> sigmoid (o).
  const float scB = (s == 0) ? 2.8853900817779268f : -1.4426950408889634f;
  const float saB = (s == 0) ? -2.0f : 1.0f;
  const float sbB = (s == 0) ? 1.0f : 0.0f;

  const PT* pca = pre2 + tid;
  const PT* pcb = pre2 + tid + 256;
  float pfa0 = (float)pca[(size_t)0 * GDIM], pfb0 = (float)pcb[(size_t)0 * GDIM];
  float pfa1 = (float)pca[(size_t)1 * GDIM], pfb1 = (float)pcb[(size_t)1 * GDIM];
  float pfa2 = (float)pca[(size_t)2 * GDIM], pfb2 = (float)pcb[(size_t)2 * GDIM];
  float pfa3 = (float)pca[(size_t)3 * GDIM], pfb3 = (float)pcb[(size_t)3 * GDIM];

  auto step = [&](int t, float& pfa, float& pfb,
                  const uint32_t* __restrict__ hbr, uint32_t* __restrict__ hbw) {
    float a0 = 0.f, a1 = 0.f, a2 = 0.f, a3 = 0.f;
    float b0 = 0.f, b1 = 0.f, b2 = 0.f, b3 = 0.f;
#pragma unroll
    for (int g = 0; g < 16; ++g) {
      uint4 hv = *(const uint4*)&hbr[4 * g];   // broadcast read
      a0 = fdot2f(wa[g].x, hv.x, a0);
      a1 = fdot2f(wa[g].y, hv.y, a1);
      a2 = fdot2f(wa[g].z, hv.z, a2);
      a3 = fdot2f(wa[g].w, hv.w, a3);
      b0 = fdot2f(wb[g].x, hv.x, b0);
      b1 = fdot2f(wb[g].y, hv.y, b1);
      b2 = fdot2f(wb[g].z, hv.z, b2);
      b3 = fdot2f(wb[g].w, hv.w, b3);
    }
    float ga = ((a0 + a1) + (a2 + a3)) + pfa;
    float gb = ((b0 + b1) + (b2 + b3)) + pfb;
    pfa = (float)pca[(size_t)(t + 4) * GDIM];  // prefetch, 4 steps ahead
    pfb = (float)pcb[(size_t)(t + 4) * GDIM];
    float ra = fast_sigmoid(ga);                               // i (s0) / f (s1)
    float eb = __builtin_amdgcn_exp2f(scB * gb);
    float rb = __builtin_amdgcn_rcpf(1.0f + eb);
    float actb = fmaf(saB, rb, sbB);                           // g (s0) / o (s1)
    float p = ra * actb;                                       // s0: i*g
    float pp = __shfl_xor(p, 1);                               // s1 receives i*g
    c = fmaf(ra, c, pp);                                       // s1: f*c + i*g
    float e2 = __builtin_amdgcn_exp2f(2.8853900817779268f * c);
    float r2 = __builtin_amdgcn_rcpf(1.0f + e2);
    float th = fmaf(-2.0f, r2, 1.0f);
    float h = actb * th;                                       // s1: o*tanh(c)
    float hp = __shfl_down(h, 2);                              // partner element
    if ((tid & 3) == 1) {
      uint32_t pk = pack2_rn(h, hp);
      hbw[tid >> 2] = pk;
      hs2p[(size_t)t * 64 + (tid >> 2)] = pk;
    }
    __syncthreads();
  };

#pragma unroll 1
  for (int t = 0; t < TSTEPS; t += 4) {
    step(t + 0, pfa0, pfb0, hpk[0], hpk[1]);
    step(t + 1, pfa1, pfb1, hpk[1], hpk[0]);
    step(t + 2, pfa2, pfb2, hpk[0], hpk[1]);
    step(t + 3, pfa3, pfb3, hpk[1], hpk[0]);
  }
}

// ---------------------------------------------------------------------------
// out = sigmoid(hs2 @ Wfc^T + bfc)
__global__ __launch_bounds__(128) void fcn_kernel(const uint32_t* __restrict__ hs2p,
                                                  const float* __restrict__ Wfc,
                                                  const float* __restrict__ bfc,
                                                  float* __restrict__ out) {
  const int n = threadIdx.x;
  uint32_t w[64];
  {
    const float4* wr = (const float4*)(Wfc + (size_t)n * FDIM);
#pragma unroll
    for (int qq = 0; qq < 32; ++qq) {
      float4 v = wr[qq];
      w[2 * qq] = pack2_rn(v.x, v.y);
      w[2 * qq + 1] = pack2_rn(v.z, v.w);
    }
  }
#pragma unroll
  for (int i = 0; i < 64; ++i) asm volatile("" : "+v"(w[i]));
  const float bias = bfc[n];
  __shared__ __align__(16) uint32_t hrow[64];
  const int tbase = blockIdx.x * 64;
#pragma unroll 1
  for (int ss = 0; ss < 64; ++ss) {
    const int t = tbase + ss;
    if (t >= TSTEPS) break;
    if (n < 64) hrow[n] = hs2p[(size_t)t * 64 + n];
    __syncthreads();
    float a0 = 0.f, a1 = 0.f, a2 = 0.f, a3 = 0.f;
#pragma unroll
    for (int qq = 0; qq < 16; ++qq) {
      uint4 hv = *(const uint4*)&hrow[4 * qq];
      a0 = fdot2f(w[4 * qq + 0], hv.x, a0);
      a1 = fdot2f(w[4 * qq + 1], hv.y, a1);
      a2 = fdot2f(w[4 * qq + 2], hv.z, a2);
      a3 = fdot2f(w[4 * qq + 3], hv.w, a3);
    }
    out[(size_t)t * FDIM + n] = fast_sigmoid((a0 + a1) + (a2 + a3) + bias);
    __syncthreads();
  }
}

// ---------------------------------------------------------------------------
extern "C" void kernel_launch(void* const* d_in, const int* in_sizes, int n_in,
                              void* d_out, int out_size, void* d_ws, size_t ws_size,
                              hipStream_t stream) {
  const float* x    = (const float*)d_in[0];
  const float* h2   = (const float*)d_in[3];
  const float* c2   = (const float*)d_in[4];
  const float* Wih2 = (const float*)d_in[9];
  const float* Whh2 = (const float*)d_in[10];
  const float* bih2 = (const float*)d_in[11];
  const float* bhh2 = (const float*)d_in[12];
  const float* Wfc  = (const float*)d_in[13];
  const float* bfc  = (const float*)d_in[14];
  float* out = (float*)d_out;

  char* ws = (char*)d_ws;
  const size_t off_whh = 0;
  const size_t sz_whh = (size_t)GDIM * 64 * 4;                 // 128 KiB
  const size_t off_hs = off_whh + sz_whh;
  const size_t sz_hs = (size_t)TSTEPS * 64 * 4;                // 12.8 MB
  const size_t off_pre = off_hs + sz_hs;
  const size_t rows = (size_t)TSTEPS + 8;                      // prefetch slack
  const size_t need_f32 = off_pre + rows * GDIM * 4;
  uint32_t* whh_pk = (uint32_t*)(ws + off_whh);
  uint32_t* hs2p = (uint32_t*)(ws + off_hs);

  const dim3 ggrid((TSTEPS + 63) / 64, GDIM / 64);

  prep_whh<<<(GDIM * (FDIM / 2) + 255) / 256, 256, 0, stream>>>(Whh2, whh_pk);

  if (ws_size >= need_f32) {
    float* pre2 = (float*)(ws + off_pre);
    pre2_gemm<float><<<ggrid, 256, 0, stream>>>(x, Wih2, bih2, bhh2, pre2);
    lstm_scan<float><<<1, 256, 0, stream>>>(pre2, whh_pk, h2, c2, hs2p);
  } else {
    _Float16* pre2 = (_Float16*)(ws + off_pre);
    pre2_gemm<_Float16><<<ggrid, 256, 0, stream>>>(x, Wih2, bih2, bhh2, pre2);
    lstm_scan<_Float16><<<1, 256, 0, stream>>>(pre2, whh_pk, h2, c2, hs2p);
  }

  fcn_kernel<<<(TSTEPS + 63) / 64, 128, 0, stream>>>(hs2p, Wfc, bfc, out);
}

// Round 4
// 30266.815 us; speedup vs baseline: 1.4003x; 1.4003x over previous
//
#include <hip/hip_runtime.h>
#include <cstdint>
#include <cstddef>

#ifndef __has_builtin
#define __has_builtin(x) 0
#endif

#define TSTEPS 50000
#define DDIM   768
#define GDIM   512   // 4*F gates
#define FDIM   128

typedef _Float16 half2_t __attribute__((ext_vector_type(2)));

__device__ __forceinline__ uint32_t pack2_rn(float a, float b) {
  uint16_t ua = __builtin_bit_cast(uint16_t, (_Float16)a);
  uint16_t ub = __builtin_bit_cast(uint16_t, (_Float16)b);
  return (uint32_t)ua | ((uint32_t)ub << 16);
}

__device__ __forceinline__ float fdot2f(uint32_t a, uint32_t b, float acc) {
#if __has_builtin(__builtin_amdgcn_fdot2)
  return __builtin_amdgcn_fdot2(__builtin_bit_cast(half2_t, a),
                                __builtin_bit_cast(half2_t, b), acc, false);
#else
  half2_t ha = __builtin_bit_cast(half2_t, a);
  half2_t hb = __builtin_bit_cast(half2_t, b);
  return acc + (float)ha[0] * (float)hb[0] + (float)ha[1] * (float)hb[1];
#endif
}

__device__ __forceinline__ float fast_sigmoid(float x) {
  float e = __builtin_amdgcn_exp2f(-1.4426950408889634f * x);
  return __builtin_amdgcn_rcpf(1.0f + e);
}

// Scan thread tid = 4j+kq reduces to gate row kq*128+j; pre2 column c holds
// original gate row ((c&3)<<7)|(c>>2) so the scan's per-step load is one
// coalesced dword per thread.
__device__ __forceinline__ int rowmap(int c) { return ((c & 3) << 7) | (c >> 2); }

// ---------------------------------------------------------------------------
// pack Whh2 (512x128 f32) -> (512x64) packed half2, original row order
__global__ __launch_bounds__(256) void prep_whh(const float* __restrict__ whh,
                                                uint32_t* __restrict__ whh_pk) {
  int idx = blockIdx.x * 256 + threadIdx.x;
  if (idx >= GDIM * (FDIM / 2)) return;
  int j = idx >> 6, q = idx & 63;
  whh_pk[idx] = pack2_rn(whh[j * FDIM + 2 * q], whh[j * FDIM + 2 * q + 1]);
}

// ---------------------------------------------------------------------------
// pre2[:, c] = x @ Wih2[rowmap(c)] + (bih2+bhh2)[rowmap(c)]
__device__ __forceinline__ void store_row4(float* p, float a, float b, float c, float d) {
  *(float4*)p = make_float4(a, b, c, d);
}
__device__ __forceinline__ void store_row4(_Float16* p, float a, float b, float c, float d) {
  uint2 v; v.x = pack2_rn(a, b); v.y = pack2_rn(c, d);
  *(uint2*)p = v;
}

template <typename PT>
__global__ __launch_bounds__(256) void pre2_gemm(const float* __restrict__ X,
                                                 const float* __restrict__ Wih,
                                                 const float* __restrict__ bih,
                                                 const float* __restrict__ bhh,
                                                 PT* __restrict__ pre2) {
  __shared__ __align__(16) float As[32][68];
  __shared__ __align__(16) float Bs[32][68];
  const int tid = threadIdx.x;
  const int m0 = blockIdx.x * 64;
  const int n0 = blockIdx.y * 64;
  const int lr = tid >> 3;
  const int lk = (tid & 7) * 4;
  const int tx = tid & 15;
  const int ty = tid >> 4;

  float acc[4][4];
#pragma unroll
  for (int i = 0; i < 4; ++i)
#pragma unroll
    for (int j = 0; j < 4; ++j) acc[i][j] = 0.0f;

  int ar0 = m0 + lr;      if (ar0 > TSTEPS - 1) ar0 = TSTEPS - 1;
  int ar1 = m0 + lr + 32; if (ar1 > TSTEPS - 1) ar1 = TSTEPS - 1;
  const int br0 = rowmap(n0 + lr), br1 = rowmap(n0 + lr + 32);

#pragma unroll 1
  for (int k0 = 0; k0 < DDIM; k0 += 32) {
    float4 a0 = *(const float4*)&X[(size_t)ar0 * DDIM + k0 + lk];
    float4 a1 = *(const float4*)&X[(size_t)ar1 * DDIM + k0 + lk];
    float4 b0 = *(const float4*)&Wih[(size_t)br0 * DDIM + k0 + lk];
    float4 b1 = *(const float4*)&Wih[(size_t)br1 * DDIM + k0 + lk];
    __syncthreads();
    As[lk + 0][lr] = a0.x; As[lk + 1][lr] = a0.y; As[lk + 2][lr] = a0.z; As[lk + 3][lr] = a0.w;
    As[lk + 0][lr + 32] = a1.x; As[lk + 1][lr + 32] = a1.y; As[lk + 2][lr + 32] = a1.z; As[lk + 3][lr + 32] = a1.w;
    Bs[lk + 0][lr] = b0.x; Bs[lk + 1][lr] = b0.y; Bs[lk + 2][lr] = b0.z; Bs[lk + 3][lr] = b0.w;
    Bs[lk + 0][lr + 32] = b1.x; Bs[lk + 1][lr + 32] = b1.y; Bs[lk + 2][lr + 32] = b1.z; Bs[lk + 3][lr + 32] = b1.w;
    __syncthreads();
#pragma unroll
    for (int kk = 0; kk < 32; ++kk) {
      float4 av = *(const float4*)&As[kk][ty * 4];
      float4 bv = *(const float4*)&Bs[kk][tx * 4];
      acc[0][0] = fmaf(av.x, bv.x, acc[0][0]); acc[0][1] = fmaf(av.x, bv.y, acc[0][1]);
      acc[0][2] = fmaf(av.x, bv.z, acc[0][2]); acc[0][3] = fmaf(av.x, bv.w, acc[0][3]);
      acc[1][0] = fmaf(av.y, bv.x, acc[1][0]); acc[1][1] = fmaf(av.y, bv.y, acc[1][1]);
      acc[1][2] = fmaf(av.y, bv.z, acc[1][2]); acc[1][3] = fmaf(av.y, bv.w, acc[1][3]);
      acc[2][0] = fmaf(av.z, bv.x, acc[2][0]); acc[2][1] = fmaf(av.z, bv.y, acc[2][1]);
      acc[2][2] = fmaf(av.z, bv.z, acc[2][2]); acc[2][3] = fmaf(av.z, bv.w, acc[2][3]);
      acc[3][0] = fmaf(av.w, bv.x, acc[3][0]); acc[3][1] = fmaf(av.w, bv.y, acc[3][1]);
      acc[3][2] = fmaf(av.w, bv.z, acc[3][2]); acc[3][3] = fmaf(av.w, bv.w, acc[3][3]);
    }
  }

  float bias[4];
#pragma unroll
  for (int jj = 0; jj < 4; ++jj) {
    int rn = rowmap(n0 + tx * 4 + jj);
    bias[jj] = bih[rn] + bhh[rn];
  }
#pragma unroll
  for (int i = 0; i < 4; ++i) {
    int m = m0 + ty * 4 + i;
    if (m < TSTEPS) {
      store_row4(&pre2[(size_t)m * GDIM + n0 + tx * 4],
                 acc[i][0] + bias[0], acc[i][1] + bias[1],
                 acc[i][2] + bias[2], acc[i][3] + bias[3]);
    }
  }
}

// ---------------------------------------------------------------------------
// Sequential LSTM scan: 1 block, 512 threads (8 waves, 2/SIMD).
// Thread tid=4j+kq: K-quarter kq (32 h values, 64 B LDS read) of ALL FOUR gate
// rows {j,128+j,256+j,384+j}. 16 NAMED uint4 weight regs (no arrays, no
// lambdas -> no scratch). Quad transpose-reduce (3 shuffles) -> thread kq
// holds gate kq of output j; 3 DPP shuffles deliver f,i*g,o to kq=0, which
// owns c_j and h_j. One barrier/step, double-buffered packed h in LDS.

#define DOT4(ACC, W, H) \
  ACC = fdot2f(W.x, H.x, ACC); ACC = fdot2f(W.y, H.y, ACC); \
  ACC = fdot2f(W.z, H.z, ACC); ACC = fdot2f(W.w, H.w, ACC)

#define PIN4(W) asm volatile("" : "+v"(W.x), "+v"(W.y), "+v"(W.z), "+v"(W.w))

#define STEP(T, PF, HBR, HBW) do {                                         \
    uint4 hv0 = *(const uint4*)&HBR[hoff + 0];                             \
    uint4 hv1 = *(const uint4*)&HBR[hoff + 4];                             \
    uint4 hv2 = *(const uint4*)&HBR[hoff + 8];                             \
    uint4 hv3 = *(const uint4*)&HBR[hoff + 12];                            \
    float aI = 0.f, aF = 0.f, aG = 0.f, aO = 0.f;                          \
    DOT4(aI, wI0, hv0); DOT4(aI, wI1, hv1); DOT4(aI, wI2, hv2); DOT4(aI, wI3, hv3); \
    DOT4(aF, wF0, hv0); DOT4(aF, wF1, hv1); DOT4(aF, wF2, hv2); DOT4(aF, wF3, hv3); \
    DOT4(aG, wG0, hv0); DOT4(aG, wG1, hv1); DOT4(aG, wG2, hv2); DOT4(aG, wG3, hv3); \
    DOT4(aO, wO0, hv0); DOT4(aO, wO1, hv1); DOT4(aO, wO2, hv2); DOT4(aO, wO3, hv3); \
    float u0 = kq1 ? aF : aI;                                              \
    float v0 = kq1 ? aI : aF;                                              \
    float u1 = kq1 ? aO : aG;                                              \
    float v1 = kq1 ? aG : aO;                                              \
    u0 += __shfl_xor(v0, 1);                                               \
    u1 += __shfl_xor(v1, 1);                                               \
    float keep = kq2 ? u1 : u0;                                            \
    float send = kq2 ? u0 : u1;                                            \
    float gate = keep + __shfl_xor(send, 2) + PF;                          \
    PF = (float)pcol[(size_t)((T) + 4) * GDIM];                            \
    float e = __builtin_amdgcn_exp2f(scA * gate);                          \
    float r = __builtin_amdgcn_rcpf(1.0f + e);                             \
    float act = fmaf(saA, r, sbA);                                         \
    float gx2 = __shfl_xor(act, 2);  /* gate kq^2 */                       \
    float gx1 = __shfl_xor(act, 1);  /* gate kq^1 */                       \
    float gx3 = __shfl_xor(gx2, 1);  /* gate kq^3 */                       \
    float prod = act * gx2;          /* kq0: i*g */                        \
    c = fmaf(gx1, c, prod);          /* valid on kq0: f*c + i*g */         \
    float e2 = __builtin_amdgcn_exp2f(2.8853900817779268f * c);            \
    float r2 = __builtin_amdgcn_rcpf(1.0f + e2);                           \
    float th = fmaf(-2.0f, r2, 1.0f);                                      \
    float h = gx3 * th;              /* valid on kq0: o*tanh(c) */         \
    float hp = __shfl_down(h, 4);                                          \
    if ((tid & 7) == 0) {                                                  \
      uint32_t pk = pack2_rn(h, hp);                                       \
      HBW[tid >> 3] = pk;                                                  \
      hs2p[(size_t)(T) * 64 + (tid >> 3)] = pk;                            \
    }                                                                      \
    __syncthreads();                                                       \
  } while (0)

template <typename PT>
__global__ __launch_bounds__(512, 2) void lstm_scan(const PT* __restrict__ pre2,
                                                    const uint32_t* __restrict__ whh_pk,
                                                    const float* __restrict__ h0,
                                                    const float* __restrict__ c0,
                                                    uint32_t* __restrict__ hs2p) {
  const int tid = threadIdx.x;    // 0..511
  const int kq = tid & 3;         // K-quarter, and final gate index
  const int j = tid >> 2;         // output element 0..127
  const int kq1 = kq & 1, kq2 = kq & 2;
  const int hoff = kq * 16;       // uint32 offset of this K-quarter in packed h

  const uint4* pw = (const uint4*)whh_pk;  // row r quarter kq at r*16 + kq*4
  const int wb = j * 16 + kq * 4;
  uint4 wI0 = pw[wb + 0],        wI1 = pw[wb + 1],        wI2 = pw[wb + 2],        wI3 = pw[wb + 3];
  uint4 wF0 = pw[2048 + wb + 0], wF1 = pw[2048 + wb + 1], wF2 = pw[2048 + wb + 2], wF3 = pw[2048 + wb + 3];
  uint4 wG0 = pw[4096 + wb + 0], wG1 = pw[4096 + wb + 1], wG2 = pw[4096 + wb + 2], wG3 = pw[4096 + wb + 3];
  uint4 wO0 = pw[6144 + wb + 0], wO1 = pw[6144 + wb + 1], wO2 = pw[6144 + wb + 2], wO3 = pw[6144 + wb + 3];
  PIN4(wI0); PIN4(wI1); PIN4(wI2); PIN4(wI3);
  PIN4(wF0); PIN4(wF1); PIN4(wF2); PIN4(wF3);
  PIN4(wG0); PIN4(wG1); PIN4(wG2); PIN4(wG3);
  PIN4(wO0); PIN4(wO1); PIN4(wO2); PIN4(wO3);

  __shared__ __align__(16) uint32_t hpk[2][64];
  float c = c0[j];                 // used only on kq==0
  if (tid < 64) hpk[0][tid] = pack2_rn(h0[2 * tid], h0[2 * tid + 1]);
  __syncthreads();

  // own activation: kq==2 (g-gate) -> tanh, else sigmoid
  const float scA = (kq == 2) ? 2.8853900817779268f : -1.4426950408889634f;
  const float saA = (kq == 2) ? -2.0f : 1.0f;
  const float sbA = (kq == 2) ? 1.0f : 0.0f;

  const PT* pcol = pre2 + tid;     // coalesced column (rowmap'ed by GEMM)
  float pf0 = (float)pcol[(size_t)0 * GDIM];
  float pf1 = (float)pcol[(size_t)1 * GDIM];
  float pf2 = (float)pcol[(size_t)2 * GDIM];
  float pf3 = (float)pcol[(size_t)3 * GDIM];

#pragma unroll 1
  for (int t = 0; t < TSTEPS; t += 4) {
    STEP(t + 0, pf0, hpk[0], hpk[1]);
    STEP(t + 1, pf1, hpk[1], hpk[0]);
    STEP(t + 2, pf2, hpk[0], hpk[1]);
    STEP(t + 3, pf3, hpk[1], hpk[0]);
  }
}

// ---------------------------------------------------------------------------
// out = sigmoid(hs2 @ Wfc^T + bfc)
__global__ __launch_bounds__(128) void fcn_kernel(const uint32_t* __restrict__ hs2p,
                                                  const float* __restrict__ Wfc,
                                                  const float* __restrict__ bfc,
                                                  float* __restrict__ out) {
  const int n = threadIdx.x;
  uint32_t w[64];
  {
    const float4* wr = (const float4*)(Wfc + (size_t)n * FDIM);
#pragma unroll
    for (int qq = 0; qq < 32; ++qq) {
      float4 v = wr[qq];
      w[2 * qq] = pack2_rn(v.x, v.y);
      w[2 * qq + 1] = pack2_rn(v.z, v.w);
    }
  }
  const float bias = bfc[n];
  __shared__ __align__(16) uint32_t hrow[64];
  const int tbase = blockIdx.x * 64;
#pragma unroll 1
  for (int ss = 0; ss < 64; ++ss) {
    const int t = tbase + ss;
    if (t >= TSTEPS) break;
    if (n < 64) hrow[n] = hs2p[(size_t)t * 64 + n];
    __syncthreads();
    float a0 = 0.f, a1 = 0.f, a2 = 0.f, a3 = 0.f;
#pragma unroll
    for (int qq = 0; qq < 16; ++qq) {
      uint4 hv = *(const uint4*)&hrow[4 * qq];
      a0 = fdot2f(w[4 * qq + 0], hv.x, a0);
      a1 = fdot2f(w[4 * qq + 1], hv.y, a1);
      a2 = fdot2f(w[4 * qq + 2], hv.z, a2);
      a3 = fdot2f(w[4 * qq + 3], hv.w, a3);
    }
    out[(size_t)t * FDIM + n] = fast_sigmoid((a0 + a1) + (a2 + a3) + bias);
    __syncthreads();
  }
}

// ---------------------------------------------------------------------------
extern "C" void kernel_launch(void* const* d_in, const int* in_sizes, int n_in,
                              void* d_out, int out_size, void* d_ws, size_t ws_size,
                              hipStream_t stream) {
  const float* x    = (const float*)d_in[0];
  const float* h2   = (const float*)d_in[3];
  const float* c2   = (const float*)d_in[4];
  const float* Wih2 = (const float*)d_in[9];
  const float* Whh2 = (const float*)d_in[10];
  const float* bih2 = (const float*)d_in[11];
  const float* bhh2 = (const float*)d_in[12];
  const float* Wfc  = (const float*)d_in[13];
  const float* bfc  = (const float*)d_in[14];
  float* out = (float*)d_out;

  char* ws = (char*)d_ws;
  const size_t off_whh = 0;
  const size_t sz_whh = (size_t)GDIM * 64 * 4;                 // 128 KiB
  const size_t off_hs = off_whh + sz_whh;
  const size_t sz_hs = (size_t)TSTEPS * 64 * 4;                // 12.8 MB
  const size_t off_pre = off_hs + sz_hs;
  const size_t rows = (size_t)TSTEPS + 8;                      // prefetch slack
  const size_t need_f32 = off_pre + rows * GDIM * 4;
  uint32_t* whh_pk = (uint32_t*)(ws + off_whh);
  uint32_t* hs2p = (uint32_t*)(ws + off_hs);

  const dim3 ggrid((TSTEPS + 63) / 64, GDIM / 64);

  prep_whh<<<(GDIM * (FDIM / 2) + 255) / 256, 256, 0, stream>>>(Whh2, whh_pk);

  if (ws_size >= need_f32) {
    float* pre2 = (float*)(ws + off_pre);
    pre2_gemm<float><<<ggrid, 256, 0, stream>>>(x, Wih2, bih2, bhh2, pre2);
    lstm_scan<float><<<1, 512, 0, stream>>>(pre2, whh_pk, h2, c2, hs2p);
  } else {
    _Float16* pre2 = (_Float16*)(ws + off_pre);
    pre2_gemm<_Float16><<<ggrid, 256, 0, stream>>>(x, Wih2, bih2, bhh2, pre2);
    lstm_scan<_Float16><<<1, 512, 0, stream>>>(pre2, whh_pk, h2, c2, hs2p);
  }

  fcn_kernel<<<(TSTEPS + 63) / 64, 128, 0, stream>>>(hs2p, Wfc, bfc, out);
}